// Round 11
// baseline (82.913 us; speedup 1.0000x reference)
//
#include <hip/hip_runtime.h>

#define I_DIM 128
#define H_DIM 64
#define BATCH 8
#define SEQ   4096
#define NBIN  (SEQ/2 + 1)     // 2049
#define NBIN2 (SEQ + 1)       // 4097

// LDS swizzle (involution, low-8-bit only -> valid for any N%256==0) — r3-r10.
#define SZ(a) ((a) ^ (((a) >> 4) & 15))

// Module-scope device scratch (graph-capture safe, fully rewritten per call).
__device__ float  g_xT[(size_t)BATCH * I_DIM * SEQ];   // x transposed, 16.8 MB
__device__ float2 g_Hh[I_DIM * NBIN];                  // K_hat, 2.1 MB
__device__ float2 g_Kf[I_DIM * NBIN2];                 // 4.2 MB
__device__ float2 g_Xf[(size_t)BATCH * I_DIM * SEQ];   // paired spectra Z, 33.5 MB
__device__ float  g_Yt[(size_t)BATCH * I_DIM * SEQ];   // y transposed, 16.8 MB

__device__ inline float2 cmul(float2 a, float2 b) {
    return make_float2(a.x * b.x - a.y * b.y, a.x * b.y + a.y * b.x);
}
__device__ inline float2 cadd(float2 a, float2 b) { return make_float2(a.x + b.x, a.y + b.y); }
__device__ inline float2 csub(float2 a, float2 b) { return make_float2(a.x - b.x, a.y - b.y); }

// DFT8 (DIF network) — proven r4-r10.
__device__ inline void dft8(float2 a[8]) {
    const float C = 0.70710678118654752f;
    float2 s0 = cadd(a[0], a[4]), s1 = cadd(a[1], a[5]);
    float2 s2 = cadd(a[2], a[6]), s3 = cadd(a[3], a[7]);
    float2 d0 = csub(a[0], a[4]), d1 = csub(a[1], a[5]);
    float2 d2 = csub(a[2], a[6]), d3 = csub(a[3], a[7]);
    d1 = make_float2(C * (d1.x + d1.y), C * (d1.y - d1.x));
    d2 = make_float2(d2.y, -d2.x);
    d3 = make_float2(C * (d3.y - d3.x), -C * (d3.x + d3.y));
    {
        float2 p0 = cadd(s0, s2), p1 = cadd(s1, s3);
        float2 m0 = csub(s0, s2), m1 = csub(s1, s3);
        m1 = make_float2(m1.y, -m1.x);
        a[0] = cadd(p0, p1); a[4] = csub(p0, p1);
        a[2] = cadd(m0, m1); a[6] = csub(m0, m1);
    }
    {
        float2 p0 = cadd(d0, d2), p1 = cadd(d1, d3);
        float2 m0 = csub(d0, d2), m1 = csub(d1, d3);
        m1 = make_float2(m1.y, -m1.x);
        a[1] = cadd(p0, p1); a[5] = csub(p0, p1);
        a[3] = cadd(m0, m1); a[7] = csub(m0, m1);
    }
}

// Radix-8 Stockham DIF stage — proven r3-r10 verbatim (now also used with
// N=8192 -> NB=1024, ITER=2).
template <int N, int S, int NT>
__device__ inline void stage8(float2* __restrict__ lds, int tid) {
    constexpr int NB = N / 8;
    constexpr int ITER = (NB + NT - 1) / NT;
    const bool act = (NB >= NT) || (tid < NB);
    float2 d[ITER][8];
#pragma unroll
    for (int b = 0; b < ITER; ++b) {
        const int u = tid + b * NT;
        if (act) {
#pragma unroll
            for (int j = 0; j < 8; ++j)
                d[b][j] = lds[SZ(u + NB * j)];
        }
    }
    __syncthreads();
#pragma unroll
    for (int b = 0; b < ITER; ++b) {
        const int u = tid + b * NT;
        if (act) {
            const int q = u & (S - 1);
            dft8(d[b]);
            if constexpr (S < NB) {
                const float cang = (float)(-6.283185307179586) / (float)N;
                float sn, cs;
                __sincosf(cang * (float)(u - q), &sn, &cs);
                const float2 w = make_float2(cs, sn);
                float2 t = w;
#pragma unroll
                for (int k = 1; k < 8; ++k) {
                    d[b][k] = cmul(d[b][k], t);
                    if (k < 7) t = cmul(t, w);
                }
            }
            const int base = 8 * u - 7 * q;
#pragma unroll
            for (int k = 0; k < 8; ++k)
                lds[SZ(base + k * S)] = d[b][k];
        }
    }
    __syncthreads();
}

// Radix-8 S=1 stage, top-half-zero inputs (a4..a7=0): b_even = DFT4(a0..a3),
// b_odd = DFT4(a0, a1*W8, a2*W8^2, a3*W8^3); twiddle W_N^{u*k}; writes
// lds[SZ(8u+k)]. Formula proven r8-r10; N templated. Caller handles barriers.
template <int N>
__device__ inline void halfzero_s1_write(float2* __restrict__ lds, int u,
                                         float2 a0, float2 a1,
                                         float2 a2, float2 a3) {
    const float C = 0.70710678118654752f;
    float2 p0 = cadd(a0, a2), p1 = cadd(a1, a3);
    float2 m0 = csub(a0, a2), m1t = csub(a1, a3);
    float2 m1 = make_float2(m1t.y, -m1t.x);
    float2 b0 = cadd(p0, p1), b4 = csub(p0, p1);
    float2 b2 = cadd(m0, m1), b6 = csub(m0, m1);
    float2 c1 = make_float2(C * (a1.x + a1.y), C * (a1.y - a1.x));
    float2 c2 = make_float2(a2.y, -a2.x);
    float2 c3 = make_float2(C * (a3.y - a3.x), -C * (a3.x + a3.y));
    float2 q0 = cadd(a0, c2), q1 = cadd(c1, c3);
    float2 n0 = csub(a0, c2), n1t = csub(c1, c3);
    float2 n1 = make_float2(n1t.y, -n1t.x);
    float2 b1 = cadd(q0, q1), b5 = csub(q0, q1);
    float2 b3 = cadd(n0, n1), b7 = csub(n0, n1);
    float sn, cs;
    __sincosf((float)(-6.283185307179586) / (float)N * (float)u, &sn, &cs);
    float2 w1 = make_float2(cs, sn);
    float2 w2 = cmul(w1, w1), w3 = cmul(w2, w1), w4 = cmul(w2, w2);
    float2 w5 = cmul(w3, w2), w6 = cmul(w3, w3), w7 = cmul(w4, w3);
    const int base = 8 * u;
    lds[SZ(base + 0)] = b0;
    lds[SZ(base + 1)] = cmul(b1, w1);
    lds[SZ(base + 2)] = cmul(b2, w2);
    lds[SZ(base + 3)] = cmul(b3, w3);
    lds[SZ(base + 4)] = cmul(b4, w4);
    lds[SZ(base + 5)] = cmul(b5, w5);
    lds[SZ(base + 6)] = cmul(b6, w6);
    lds[SZ(base + 7)] = cmul(b7, w7);
}

// Full radix-8 S=1 stage from register inputs: dft8 + W_N^{u*k} + write.
template <int N>
__device__ inline void full_s1_write(float2* __restrict__ lds, int u, float2 d[8]) {
    dft8(d);
    float sn, cs;
    __sincosf((float)(-6.283185307179586) / (float)N * (float)u, &sn, &cs);
    float2 w1 = make_float2(cs, sn);
    float2 w2 = cmul(w1, w1), w3 = cmul(w2, w1), w4 = cmul(w2, w2);
    float2 w5 = cmul(w3, w2), w6 = cmul(w3, w3), w7 = cmul(w4, w3);
    const int base = 8 * u;
    lds[SZ(base + 0)] = d[0];
    lds[SZ(base + 1)] = cmul(d[1], w1);
    lds[SZ(base + 2)] = cmul(d[2], w2);
    lds[SZ(base + 3)] = cmul(d[3], w3);
    lds[SZ(base + 4)] = cmul(d[4], w4);
    lds[SZ(base + 5)] = cmul(d[5], w5);
    lds[SZ(base + 6)] = cmul(d[6], w6);
    lds[SZ(base + 7)] = cmul(d[7], w7);
}

// K_hat single bin — proven r2-r10.
__device__ inline float2 khat_bin(int i, int k,
                                  const float* __restrict__ Bm,
                                  const float* __restrict__ Cm,
                                  const float* __restrict__ Lm,
                                  const float* __restrict__ Pm,
                                  const float* __restrict__ Qm) {
    float theta = (float)(6.283185307179586 / (double)SEQ) * (float)k;
    float sn, cs;
    sincosf(theta, &sn, &cs);
    float tr = 1.0f - cs, ti = -sn;
    float br = 1.0f + cs, bi = sn;
    float idn = 1.0f / (br * br + bi * bi);
    float gr = 20.0f * (tr * br + ti * bi) * idn;
    float gi = 20.0f * (ti * br - tr * bi) * idn;
    float cr = 2.0f * br * idn;
    float ci = -2.0f * bi * idn;

    const float* Brow = Bm + i * H_DIM;
    const float* Crow = Cm + i * H_DIM;
    const float* Lrow = Lm + i * H_DIM;
    const float* Prow = Pm + i * H_DIM;
    const float* Qrow = Qm + i * H_DIM;

    float k00r = 0.f, k00i = 0.f, k01r = 0.f, k01i = 0.f;
    float k10r = 0.f, k10i = 0.f, k11r = 0.f, k11i = 0.f;
#pragma unroll 8
    for (int h = 0; h < H_DIM; ++h) {
        float lam = Lrow[h];
        float drr = gr - lam;
        float dii = gi;
        float im = 1.0f / (drr * drr + dii * dii);
        float ivr = drr * im;
        float ivi = -dii * im;
        float bv = Brow[h], cv = Crow[h], pv = Prow[h], qv = Qrow[h];
        float cb = cv * bv;
        float cp = cv * pv;
        float qb = qv * bv;
        float qp = qv * pv;
        k00r += cb * ivr; k00i += cb * ivi;
        k01r += cp * ivr; k01i += cp * ivi;
        k10r += qb * ivr; k10i += qb * ivi;
        k11r += qp * ivr; k11i += qp * ivi;
    }
    float t1r = 1.0f + k11r, t1i = k11i;
    float t2r = k01r * t1r - k01i * t1i;
    float t2i = k01r * t1i + k01i * t1r;
    float t3r = t2r * k10r - t2i * k10i;
    float t3i = t2r * k10i + t2i * k10r;
    float nr = k00r - t3r, ni = k00i - t3i;
    return make_float2(cr * nr - ci * ni, cr * ni + ci * nr);
}

// ===========================================================================
// Kernel 1: tiled transpose x -> xT + khat spread over 1024 blocks (r10).
// ===========================================================================
__global__ __launch_bounds__(256) void k1_transpose_khat(const float* __restrict__ x,
                                                         const float* __restrict__ Bm,
                                                         const float* __restrict__ Cm,
                                                         const float* __restrict__ Lm,
                                                         const float* __restrict__ Pm,
                                                         const float* __restrict__ Qm) {
    __shared__ float t[64][65];
    const int blk = blockIdx.x;
    const int b = blk >> 7;
    const int rest = blk & 127;
    const int nt = rest >> 1;
    const int it = rest & 1;
    const int tx = threadIdx.x & 63;
    const int ty = threadIdx.x >> 6;
    const int n0 = nt * 64, i0 = it * 64;

    const float* xb = x + (size_t)b * SEQ * I_DIM;
#pragma unroll
    for (int r = 0; r < 16; ++r) {
        int nl = r * 4 + ty;
        t[nl][tx] = xb[(size_t)(n0 + nl) * I_DIM + i0 + tx];
    }
    __syncthreads();
#pragma unroll
    for (int r = 0; r < 16; ++r) {
        int il = r * 4 + ty;
        g_xT[((size_t)b * I_DIM + i0 + il) * SEQ + n0 + tx] = t[tx][il];
    }

    const int ch = blk >> 3, sl = blk & 7;
    const int k = sl * 256 + threadIdx.x;
    g_Hh[(size_t)ch * NBIN + k] = khat_bin(ch, k, Bm, Cm, Lm, Pm, Qm);
    if (sl == 0 && threadIdx.x == 0)
        g_Hh[(size_t)ch * NBIN + 2048] = khat_bin(ch, 2048, Bm, Cm, Lm, Pm, Qm);
}

// ===========================================================================
// Kernel 2: blocks [0,64)   -> PAIRED kprep: channels (g, g+64).
//             H' = HA + j*HB (Hermitian-extended) -> icfft4096 (conj trick)
//             -> kA + j*kB -> zero-pad -> cfft8192 -> Hermitian split -> Kf.
//           blocks [64,576) -> PAIRED fwd: z = xA + j*xB zero-padded,
//             Z = cfft8192(z) -> g_Xf (last r2 stage fused with store).
// ===========================================================================
__global__ __launch_bounds__(512) void k2_kprep_fwd() {
    __shared__ float2 L[8192];           // 64 KB
    const int tid = threadIdx.x;

    if (blockIdx.x < 64) {
        const int g = blockIdx.x;
        const float2* HA = g_Hh + (size_t)g * NBIN;
        const float2* HB = g_Hh + (size_t)(g + 64) * NBIN;

        // fused-in: c[m] = conj(HA[m] + j*HB[m]), icfft4096 stage S=1 (u=tid)
        float2 d[8];
#pragma unroll
        for (int j = 0; j < 8; ++j) {
            int m = tid + (j << 9);      // 0..4095
            float2 hA, hB;
            if (m <= 2048) { hA = HA[m]; hB = HB[m]; }
            else {
                float2 tA = HA[4096 - m], tB = HB[4096 - m];
                hA = make_float2(tA.x, -tA.y);
                hB = make_float2(tB.x, -tB.y);
            }
            // H' = (hA.x - hB.y, hA.y + hB.x); store conj(H')
            d[j] = make_float2(hA.x - hB.y, -(hA.y + hB.x));
        }
        full_s1_write<4096>(L, tid, d);
        __syncthreads();

        stage8<4096, 8,   512>(L, tid);
        stage8<4096, 64,  512>(L, tid);
        stage8<4096, 512, 512>(L, tid);

        // v[n] = conj(R[n])/4096 = kA[n] + j*kB[n]; fused halfzero8192 stage
        const float s1 = 1.0f / 4096.0f;
        float2 va[2][4];
#pragma unroll
        for (int b2 = 0; b2 < 2; ++b2)
#pragma unroll
            for (int j = 0; j < 4; ++j) {
                int n = tid + (b2 << 9) + (j << 10);   // < 4096
                float2 o = L[SZ(n)];
                va[b2][j] = make_float2(o.x * s1, -o.y * s1);
            }
        __syncthreads();
#pragma unroll
        for (int b2 = 0; b2 < 2; ++b2)
            halfzero_s1_write<8192>(L, tid + (b2 << 9),
                                    va[b2][0], va[b2][1], va[b2][2], va[b2][3]);
        __syncthreads();

        stage8<8192, 8,   512>(L, tid);
        stage8<8192, 64,  512>(L, tid);
        stage8<8192, 512, 512>(L, tid);

        // fused final r2 (S=4096, twiddle-free) + Hermitian split -> Kf rows.
        // Zf[m] = L[m] + L[m+4096] (m<4096); Zf[8192-m] = L[4096-m] - L[8192-m].
        float2* KfA = g_Kf + (size_t)g * NBIN2;
        float2* KfB = g_Kf + (size_t)(g + 64) * NBIN2;
#pragma unroll
        for (int r = 0; r < 8; ++r) {
            int m = tid + (r << 9);      // 0..4095
            float2 A0 = L[SZ(m)], A1 = L[SZ(m + 4096)];
            float2 P = cadd(A0, A1);
            float2 Q;
            if (m == 0) Q = P;
            else {
                float2 B0 = L[SZ(4096 - m)], B1 = L[SZ(8192 - m)];
                Q = csub(B0, B1);
            }
            KfA[m] = make_float2(0.5f * (P.x + Q.x), 0.5f * (P.y - Q.y));
            float dxr = P.x - Q.x, dyr = P.y + Q.y;
            KfB[m] = make_float2(0.5f * dyr, -0.5f * dxr);
        }
        if (tid == 0) {
            float2 P = csub(L[SZ(0)], L[SZ(4096)]);    // Zf[4096]
            KfA[4096] = make_float2(P.x, 0.f);
            KfB[4096] = make_float2(P.y, 0.f);
        }
    } else {
        // ---------------- paired forward FFT ----------------
        const int blk = blockIdx.x - 64;     // 0..511
        const int b = blk & 7;               // batch -> XCD affinity
        const int g = blk >> 3;              // 0..63
        const float* xrA = g_xT + ((size_t)b * I_DIM + g) * SEQ;
        const float* xrB = g_xT + ((size_t)b * I_DIM + g + 64) * SEQ;

        float2 va[2][4];
#pragma unroll
        for (int b2 = 0; b2 < 2; ++b2)
#pragma unroll
            for (int j = 0; j < 4; ++j) {
                int n = tid + (b2 << 9) + (j << 10);   // < 4096
                va[b2][j] = make_float2(xrA[n], xrB[n]);
            }
#pragma unroll
        for (int b2 = 0; b2 < 2; ++b2)
            halfzero_s1_write<8192>(L, tid + (b2 << 9),
                                    va[b2][0], va[b2][1], va[b2][2], va[b2][3]);
        __syncthreads();

        stage8<8192, 8,   512>(L, tid);
        stage8<8192, 64,  512>(L, tid);
        stage8<8192, 512, 512>(L, tid);

        // fused final r2 + coalesced Z store
        float2* dst = g_Xf + (size_t)blk * 2 * SEQ;    // 8192 bins
#pragma unroll
        for (int r = 0; r < 8; ++r) {
            int u = tid + (r << 9);      // 0..4095
            float2 A0 = L[SZ(u)], A1 = L[SZ(u + 4096)];
            dst[u]        = cadd(A0, A1);
            dst[u + 4096] = csub(A0, A1);
        }
    }
}

// ===========================================================================
// Kernel 3: paired combine + inverse cfft8192 -> yT rows (g, g+64).
//   XA = (Z[m]+conj(Z[-m]))/2, XB = -j/2*(Z[m]-conj(Z[-m]));
//   W = XA*KfA + j*(XB*KfB); icfft via conj trick; final r2 fused with store.
// ===========================================================================
__global__ __launch_bounds__(512) void k3_combine_inv() {
    __shared__ float2 L[8192];
    const int tid = threadIdx.x;
    const int blk = blockIdx.x;          // 0..511
    const int b = blk & 7;
    const int g = blk >> 3;
    const float2* Z = g_Xf + (size_t)blk * 2 * SEQ;
    const float2* KfA = g_Kf + (size_t)g * NBIN2;
    const float2* KfB = g_Kf + (size_t)(g + 64) * NBIN2;

    float2 d[2][8];
#pragma unroll
    for (int b2 = 0; b2 < 2; ++b2) {
        const int u = tid + (b2 << 9);
#pragma unroll
        for (int j = 0; j < 8; ++j) {
            int m = u + (j << 10);       // 0..8191
            float2 P = Z[m];
            float2 Q = (m == 0) ? P : Z[8192 - m];
            float2 XA = make_float2(0.5f * (P.x + Q.x), 0.5f * (P.y - Q.y));
            float dxr = P.x - Q.x, dyr = P.y + Q.y;
            float2 XB = make_float2(0.5f * dyr, -0.5f * dxr);
            float2 KA, KB;
            if (m <= 4096) { KA = KfA[m]; KB = KfB[m]; }
            else {
                float2 tA = KfA[8192 - m], tB = KfB[8192 - m];
                KA = make_float2(tA.x, -tA.y);
                KB = make_float2(tB.x, -tB.y);
            }
            float2 YA = cmul(XA, KA);
            float2 YB = cmul(XB, KB);
            // W = YA + j*YB; store conj(W)
            d[b2][j] = make_float2(YA.x - YB.y, -(YA.y + YB.x));
        }
    }
#pragma unroll
    for (int b2 = 0; b2 < 2; ++b2)
        full_s1_write<8192>(L, tid + (b2 << 9), d[b2]);
    __syncthreads();

    stage8<8192, 8,   512>(L, tid);
    stage8<8192, 64,  512>(L, tid);
    stage8<8192, 512, 512>(L, tid);

    // fused final r2 + unpack: w[n] = conj(F[n])/8192, yA = w.x, yB = w.y;
    // only n < 4096 needed (first SEQ samples).
    const float inv = 1.0f / 8192.0f;
    float* yA = g_Yt + ((size_t)b * I_DIM + g) * SEQ;
    float* yB = g_Yt + ((size_t)b * I_DIM + g + 64) * SEQ;
#pragma unroll
    for (int r = 0; r < 8; ++r) {
        int n = tid + (r << 9);          // 0..4095
        float2 F = cadd(L[SZ(n)], L[SZ(n + 4096)]);
        yA[n] = F.x * inv;
        yB[n] = -F.y * inv;
    }
}

// ===========================================================================
// Kernel 4: tiled transpose yT -> y (r10 verbatim).
// ===========================================================================
__global__ __launch_bounds__(256) void k4_transpose_out(float* __restrict__ y) {
    __shared__ float t[64][65];
    const int blk = blockIdx.x;
    const int b = blk >> 7;
    const int rest = blk & 127;
    const int nt = rest >> 1;
    const int it = rest & 1;
    const int tx = threadIdx.x & 63;
    const int ty = threadIdx.x >> 6;
    const int n0 = nt * 64, i0 = it * 64;

#pragma unroll
    for (int r = 0; r < 16; ++r) {
        int il = r * 4 + ty;
        t[il][tx] = g_Yt[((size_t)b * I_DIM + i0 + il) * SEQ + n0 + tx];
    }
    __syncthreads();
    float* yb = y + (size_t)b * SEQ * I_DIM;
#pragma unroll
    for (int r = 0; r < 16; ++r) {
        int nl = r * 4 + ty;
        yb[(size_t)(n0 + nl) * I_DIM + i0 + tx] = t[tx][nl];
    }
}

// ---------------------------------------------------------------------------
extern "C" void kernel_launch(void* const* d_in, const int* in_sizes, int n_in,
                              void* d_out, int out_size, void* d_ws, size_t ws_size,
                              hipStream_t stream) {
    const float* x  = (const float*)d_in[0];
    const float* Bm = (const float*)d_in[1];
    const float* Cm = (const float*)d_in[2];
    const float* Lm = (const float*)d_in[3];
    const float* Pm = (const float*)d_in[4];
    const float* Qm = (const float*)d_in[5];
    float* out = (float*)d_out;

    k1_transpose_khat<<<1024, 256, 0, stream>>>(x, Bm, Cm, Lm, Pm, Qm);
    k2_kprep_fwd<<<64 + 512, 512, 0, stream>>>();
    k3_combine_inv<<<512, 512, 0, stream>>>();
    k4_transpose_out<<<1024, 256, 0, stream>>>(out);
}

// Round 12
// 79.554 us; speedup vs baseline: 1.0422x; 1.0422x over previous
//
#include <hip/hip_runtime.h>

#define I_DIM 128
#define H_DIM 64
#define BATCH 8
#define SEQ   4096
#define NBIN  (SEQ/2 + 1)     // 2049
#define NBIN2 (SEQ + 1)       // 4097

// LDS swizzle (involution) — proven r3-r11.
#define SZ(a) ((a) ^ (((a) >> 4) & 15))

// Module-scope device scratch (graph-capture safe, fully rewritten per call).
__device__ float  g_xT[(size_t)BATCH * I_DIM * SEQ];   // x transposed, 16.8 MB
__device__ float2 g_Kf[I_DIM * NBIN2];                 // 4.2 MB
__device__ float  g_Yt[(size_t)BATCH * I_DIM * SEQ];   // y transposed, 16.8 MB

__device__ inline float2 cmul(float2 a, float2 b) {
    return make_float2(a.x * b.x - a.y * b.y, a.x * b.y + a.y * b.x);
}
__device__ inline float2 cadd(float2 a, float2 b) { return make_float2(a.x + b.x, a.y + b.y); }
__device__ inline float2 csub(float2 a, float2 b) { return make_float2(a.x - b.x, a.y - b.y); }

// DFT8 / DFT4 — proven r4-r11.
__device__ inline void dft8(float2 a[8]) {
    const float C = 0.70710678118654752f;
    float2 s0 = cadd(a[0], a[4]), s1 = cadd(a[1], a[5]);
    float2 s2 = cadd(a[2], a[6]), s3 = cadd(a[3], a[7]);
    float2 d0 = csub(a[0], a[4]), d1 = csub(a[1], a[5]);
    float2 d2 = csub(a[2], a[6]), d3 = csub(a[3], a[7]);
    d1 = make_float2(C * (d1.x + d1.y), C * (d1.y - d1.x));
    d2 = make_float2(d2.y, -d2.x);
    d3 = make_float2(C * (d3.y - d3.x), -C * (d3.x + d3.y));
    {
        float2 p0 = cadd(s0, s2), p1 = cadd(s1, s3);
        float2 m0 = csub(s0, s2), m1 = csub(s1, s3);
        m1 = make_float2(m1.y, -m1.x);
        a[0] = cadd(p0, p1); a[4] = csub(p0, p1);
        a[2] = cadd(m0, m1); a[6] = csub(m0, m1);
    }
    {
        float2 p0 = cadd(d0, d2), p1 = cadd(d1, d3);
        float2 m0 = csub(d0, d2), m1 = csub(d1, d3);
        m1 = make_float2(m1.y, -m1.x);
        a[1] = cadd(p0, p1); a[5] = csub(p0, p1);
        a[3] = cadd(m0, m1); a[7] = csub(m0, m1);
    }
}

__device__ inline void dft4(float2 a[4]) {
    float2 p0 = cadd(a[0], a[2]), p1 = cadd(a[1], a[3]);
    float2 m0 = csub(a[0], a[2]), m1 = csub(a[1], a[3]);
    m1 = make_float2(m1.y, -m1.x);
    a[0] = cadd(p0, p1); a[2] = csub(p0, p1);
    a[1] = cadd(m0, m1); a[3] = csub(m0, m1);
}

// Radix-8 Stockham DIF stage — proven r3-r11, verbatim.
template <int N, int S, int NT>
__device__ inline void stage8(float2* __restrict__ lds, int tid) {
    constexpr int NB = N / 8;
    constexpr int ITER = (NB + NT - 1) / NT;
    const bool act = (NB >= NT) || (tid < NB);
    float2 d[ITER][8];
#pragma unroll
    for (int b = 0; b < ITER; ++b) {
        const int u = tid + b * NT;
        if (act) {
#pragma unroll
            for (int j = 0; j < 8; ++j)
                d[b][j] = lds[SZ(u + NB * j)];
        }
    }
    __syncthreads();
#pragma unroll
    for (int b = 0; b < ITER; ++b) {
        const int u = tid + b * NT;
        if (act) {
            const int q = u & (S - 1);
            dft8(d[b]);
            if constexpr (S < NB) {
                const float cang = (float)(-6.283185307179586) / (float)N;
                float sn, cs;
                __sincosf(cang * (float)(u - q), &sn, &cs);
                const float2 w = make_float2(cs, sn);
                float2 t = w;
#pragma unroll
                for (int k = 1; k < 8; ++k) {
                    d[b][k] = cmul(d[b][k], t);
                    if (k < 7) t = cmul(t, w);
                }
            }
            const int base = 8 * u - 7 * q;
#pragma unroll
            for (int k = 0; k < 8; ++k)
                lds[SZ(base + k * S)] = d[b][k];
        }
    }
    __syncthreads();
}

// First stage of cfft4096 with zero top half — proven r8-r10. Leading
// barrier protects the caller's prior LDS reads.
__device__ inline void halfzero4096_writeback(float2* __restrict__ lds, int tid,
                                              float2 a0, float2 a1,
                                              float2 a2, float2 a3) {
    const float C = 0.70710678118654752f;
    __syncthreads();
    float2 p0 = cadd(a0, a2), p1 = cadd(a1, a3);
    float2 m0 = csub(a0, a2), m1t = csub(a1, a3);
    float2 m1 = make_float2(m1t.y, -m1t.x);
    float2 b0 = cadd(p0, p1), b4 = csub(p0, p1);
    float2 b2 = cadd(m0, m1), b6 = csub(m0, m1);
    float2 c1 = make_float2(C * (a1.x + a1.y), C * (a1.y - a1.x));
    float2 c2 = make_float2(a2.y, -a2.x);
    float2 c3 = make_float2(C * (a3.y - a3.x), -C * (a3.x + a3.y));
    float2 q0 = cadd(a0, c2), q1 = cadd(c1, c3);
    float2 n0 = csub(a0, c2), n1t = csub(c1, c3);
    float2 n1 = make_float2(n1t.y, -n1t.x);
    float2 b1 = cadd(q0, q1), b5 = csub(q0, q1);
    float2 b3 = cadd(n0, n1), b7 = csub(n0, n1);
    float sn, cs;
    __sincosf((float)(-6.283185307179586 / 4096.0) * (float)tid, &sn, &cs);
    float2 w1 = make_float2(cs, sn);
    float2 w2 = cmul(w1, w1), w3 = cmul(w2, w1), w4 = cmul(w2, w2);
    float2 w5 = cmul(w3, w2), w6 = cmul(w3, w3), w7 = cmul(w4, w3);
    const int base = 8 * tid;
    lds[SZ(base + 0)] = b0;
    lds[SZ(base + 1)] = cmul(b1, w1);
    lds[SZ(base + 2)] = cmul(b2, w2);
    lds[SZ(base + 3)] = cmul(b3, w3);
    lds[SZ(base + 4)] = cmul(b4, w4);
    lds[SZ(base + 5)] = cmul(b5, w5);
    lds[SZ(base + 6)] = cmul(b6, w6);
    lds[SZ(base + 7)] = cmul(b7, w7);
    __syncthreads();
}

// ===========================================================================
// Kernel 1: blocks [0,128)   -> self-contained K-chain (khat row -> LDS ->
//                               icfft2048 -> cfft4096 -> untwist -> Kf),
//                               verbatim R9 (proven).
//           blocks [128,1152) -> tiled transpose x -> xT (512 threads).
// ===========================================================================
__global__ __launch_bounds__(512) void k1_kprep_transpose(const float* __restrict__ x,
                                                          const float* __restrict__ Bm,
                                                          const float* __restrict__ Cm,
                                                          const float* __restrict__ Lm,
                                                          const float* __restrict__ Pm,
                                                          const float* __restrict__ Qm) {
    const int tid = threadIdx.x;

    if (blockIdx.x < I_DIM) {
        __shared__ float2 lds[4096];
        const int i = blockIdx.x;

        // ---- phase 0: khat row i -> lds[k] (plain indices) ----
        {
            const float* Brow = Bm + i * H_DIM;
            const float* Crow = Cm + i * H_DIM;
            const float* Lrow = Lm + i * H_DIM;
            const float* Prow = Pm + i * H_DIM;
            const float* Qrow = Qm + i * H_DIM;
            for (int k = tid; k < NBIN; k += 512) {
                float theta = (float)(6.283185307179586 / (double)SEQ) * (float)k;
                float sn, cs;
                sincosf(theta, &sn, &cs);
                float tr = 1.0f - cs, ti = -sn;
                float br = 1.0f + cs, bi = sn;
                float idn = 1.0f / (br * br + bi * bi);
                float gr = 20.0f * (tr * br + ti * bi) * idn;
                float gi = 20.0f * (ti * br - tr * bi) * idn;
                float cr = 2.0f * br * idn;
                float ci = -2.0f * bi * idn;

                float k00r = 0.f, k00i = 0.f, k01r = 0.f, k01i = 0.f;
                float k10r = 0.f, k10i = 0.f, k11r = 0.f, k11i = 0.f;
#pragma unroll 8
                for (int h = 0; h < H_DIM; ++h) {
                    float lam = Lrow[h];
                    float drr = gr - lam;
                    float dii = gi;
                    float im = 1.0f / (drr * drr + dii * dii);
                    float ivr = drr * im;
                    float ivi = -dii * im;
                    float bv = Brow[h], cv = Crow[h], pv = Prow[h], qv = Qrow[h];
                    float cb = cv * bv;
                    float cp = cv * pv;
                    float qb = qv * bv;
                    float qp = qv * pv;
                    k00r += cb * ivr; k00i += cb * ivi;
                    k01r += cp * ivr; k01i += cp * ivi;
                    k10r += qb * ivr; k10i += qb * ivi;
                    k11r += qp * ivr; k11i += qp * ivi;
                }
                float t1r = 1.0f + k11r, t1i = k11i;
                float t2r = k01r * t1r - k01i * t1i;
                float t2i = k01r * t1i + k01i * t1r;
                float t3r = t2r * k10r - t2i * k10i;
                float t3i = t2r * k10i + t2i * k10r;
                float nr = k00r - t3r, ni = k00i - t3i;
                lds[k] = make_float2(cr * nr - ci * ni, cr * ni + ci * nr);
            }
        }
        __syncthreads();

        // ---- fused icfft2048 first stage (radix-4, S=1) + pack (r9) ----
        {
            float2 z[4];
#pragma unroll
            for (int j = 0; j < 4; ++j) {
                int m = tid + (j << 9);
                float2 Hm = lds[m];
                float2 Hc = lds[2048 - m];
                float pr = Hm.x + Hc.x, pi2 = Hm.y - Hc.y;
                float dr = Hm.x - Hc.x, di = Hm.y + Hc.y;
                float sn, cs;
                __sincosf((float)(3.141592653589793 / 2048.0) * (float)m, &sn, &cs);
                float Or = 0.5f * (cs * dr - sn * di);
                float Oi = 0.5f * (sn * dr + cs * di);
                z[j] = make_float2(0.5f * pr - Oi, -(0.5f * pi2 + Or));
            }
            __syncthreads();
            dft4(z);
            float sn, cs;
            __sincosf((float)(-6.283185307179586 / 2048.0) * (float)tid, &sn, &cs);
            float2 w1 = make_float2(cs, sn);
            float2 w2 = cmul(w1, w1);
            float2 w3 = cmul(w2, w1);
            z[1] = cmul(z[1], w1);
            z[2] = cmul(z[2], w2);
            z[3] = cmul(z[3], w3);
            const int base = 4 * tid;
#pragma unroll
            for (int k = 0; k < 4; ++k) lds[SZ(base + k)] = z[k];
            __syncthreads();
        }

        stage8<2048, 4,   512>(lds, tid);
        stage8<2048, 32,  512>(lds, tid);
        stage8<2048, 256, 512>(lds, tid);

        // ---- fused v-pack (conj/2048) + cfft4096 halfzero first stage ----
        {
            const float s1 = 1.0f / 2048.0f;
            float2 a[4];
#pragma unroll
            for (int j = 0; j < 4; ++j) {
                float2 o = lds[SZ(tid + (j << 9))];
                a[j] = make_float2(o.x * s1, -o.y * s1);
            }
            halfzero4096_writeback(lds, tid, a[0], a[1], a[2], a[3]);
        }

        stage8<4096, 8,   512>(lds, tid);
        stage8<4096, 64,  512>(lds, tid);
        stage8<4096, 512, 512>(lds, tid);

        // ---- untwist -> Kf (r9 verbatim) ----
        float2* Kfrow = g_Kf + (size_t)i * NBIN2;
#pragma unroll
        for (int r = 0; r < 9; ++r) {
            int m = tid + (r << 9);
            if (m <= 4096) {
                float2 Zq = lds[SZ(m & 4095)];
                float2 Zr = lds[SZ((4096 - m) & 4095)];
                float sn, cs;
                __sincosf((float)(-3.141592653589793 / 4096.0) * (float)m, &sn, &cs);
                float pr = Zq.x + Zr.x, pi2 = Zq.y - Zr.y;
                float dr = Zq.x - Zr.x, di = Zq.y + Zr.y;
                float jt_r = -sn * dr - cs * di;
                float jt_i =  cs * dr - sn * di;
                Kfrow[m] = make_float2(0.5f * (pr - jt_r), 0.5f * (pi2 - jt_i));
            }
        }
    } else {
        // ---- tiled transpose x[b][n][i] -> xT[b][i][n], 512 threads ----
        __shared__ float t[64][65];
        const int blk = blockIdx.x - I_DIM;  // 0..1023
        const int b = blk >> 7;
        const int rest = blk & 127;
        const int nt = rest >> 1;            // 0..63
        const int it = rest & 1;             // 0..1
        const int tx = tid & 63;
        const int ty = tid >> 6;             // 0..7
        const int n0 = nt * 64, i0 = it * 64;

        const float* xb = x + (size_t)b * SEQ * I_DIM;
#pragma unroll
        for (int r = 0; r < 8; ++r) {
            int nl = r * 8 + ty;
            t[nl][tx] = xb[(size_t)(n0 + nl) * I_DIM + i0 + tx];   // coalesced in i
        }
        __syncthreads();
#pragma unroll
        for (int r = 0; r < 8; ++r) {
            int il = r * 8 + ty;
            g_xT[((size_t)b * I_DIM + i0 + il) * SEQ + n0 + tx] = t[tx][il];  // coalesced in n
        }
    }
}

// ===========================================================================
// Kernel 2: FUSED conv per (b,i):
//   coalesced xT load -> fwd cfft4096 (halfzero S1 fused) -> S8, S64, S512
//   -> combine + inverse-S1 fused in registers (r9-proven formula, pairs
//      read from LDS) -> S8, S64 -> final dft8 fused with coalesced yT store.
// ===========================================================================
__global__ __launch_bounds__(512) void k2_fused_conv() {
    __shared__ float2 L[4096];
    const int tid = threadIdx.x;
    const int blk = blockIdx.x;          // 0..1023
    const int b = blk & 7;               // batch -> XCD affinity
    const int i = blk >> 3;

    // coalesced pack: z[n] = xT[2n] + j*xT[2n+1] = float2 load
    const float2* xrow = (const float2*)(g_xT + ((size_t)b * I_DIM + i) * SEQ);
    float2 a0 = xrow[tid];
    float2 a1 = xrow[tid + 512];
    float2 a2 = xrow[tid + 1024];
    float2 a3 = xrow[tid + 1536];
    halfzero4096_writeback(L, tid, a0, a1, a2, a3);

    stage8<4096, 8,   512>(L, tid);
    stage8<4096, 64,  512>(L, tid);
    stage8<4096, 512, 512>(L, tid);      // Zx natural order in LDS

    // ---- combine + inverse S1, fused in registers (r9 formula) ----
    const float2* Kfrow = g_Kf + (size_t)i * NBIN2;
    float2 d[8];
#pragma unroll
    for (int j = 0; j < 8; ++j) {
        int m = tid + (j << 9);
        int mm = (4096 - m) & 4095;
        float2 Zq = L[SZ(m)];
        float2 Zr = L[SZ(mm)];
        float2 Km  = Kfrow[m];
        float2 Km2 = Kfrow[4096 - m];
        float sn, cs;
        __sincosf((float)(-3.141592653589793 / 4096.0) * (float)m, &sn, &cs);
        float pr = Zq.x + Zr.x, pi2 = Zq.y - Zr.y;
        float dr = Zq.x - Zr.x, di = Zq.y + Zr.y;
        float jt_r = -sn * dr - cs * di;
        float jt_i =  cs * dr - sn * di;
        float2 Xm  = make_float2(0.5f * (pr - jt_r),  0.5f * ( pi2 - jt_i));
        float2 Xm2 = make_float2(0.5f * (pr + jt_r),  0.5f * (-pi2 - jt_i));
        float2 Ym  = cmul(Xm,  Km);
        float2 Ym2 = cmul(Xm2, Km2);
        float qr = Ym.x + Ym2.x, qi = Ym.y - Ym2.y;
        float er = Ym.x - Ym2.x, ei = Ym.y + Ym2.y;
        float gr2 = sn * er - cs * ei;
        float gi2 = sn * ei + cs * er;
        d[j] = make_float2(0.5f * (qr + gr2), -0.5f * (qi + gi2));  // conjZy[m]
    }
    __syncthreads();                     // all pair-reads done before overwrite

    // inverse stage 1 (S=1): dft8 + W4096^(tid*k), write SZ(8*tid+k) (r9)
    dft8(d);
    {
        float sn, cs;
        __sincosf((float)(-6.283185307179586 / 4096.0) * (float)tid, &sn, &cs);
        float2 w1 = make_float2(cs, sn);
        float2 w2 = cmul(w1, w1), w3 = cmul(w2, w1), w4 = cmul(w2, w2);
        float2 w5 = cmul(w3, w2), w6 = cmul(w3, w3), w7 = cmul(w4, w3);
        d[1] = cmul(d[1], w1); d[2] = cmul(d[2], w2); d[3] = cmul(d[3], w3);
        d[4] = cmul(d[4], w4); d[5] = cmul(d[5], w5); d[6] = cmul(d[6], w6);
        d[7] = cmul(d[7], w7);
    }
    const int base = 8 * tid;
#pragma unroll
    for (int k = 0; k < 8; ++k) L[SZ(base + k)] = d[k];
    __syncthreads();

    stage8<4096, 8,  512>(L, tid);
    stage8<4096, 64, 512>(L, tid);

    // last stage (S=512, twiddle-free) fused with coalesced yT store (r10)
    float2 e[8];
#pragma unroll
    for (int j = 0; j < 8; ++j) e[j] = L[SZ(tid + (j << 9))];
    dft8(e);
    const float inv = 1.0f / 4096.0f;
    float2* yrow = (float2*)(g_Yt + ((size_t)b * I_DIM + i) * SEQ);
#pragma unroll
    for (int k = 0; k < 4; ++k)
        yrow[tid + (k << 9)] = make_float2(e[k].x * inv, -e[k].y * inv);
}

// ===========================================================================
// Kernel 3: tiled transpose yT[b][i][n] -> y[b][n][i] (r10 k4 verbatim).
// ===========================================================================
__global__ __launch_bounds__(256) void k3_transpose_out(float* __restrict__ y) {
    __shared__ float t[64][65];
    const int blk = blockIdx.x;          // 0..1023
    const int b = blk >> 7;
    const int rest = blk & 127;
    const int nt = rest >> 1;
    const int it = rest & 1;
    const int tx = threadIdx.x & 63;
    const int ty = threadIdx.x >> 6;
    const int n0 = nt * 64, i0 = it * 64;

#pragma unroll
    for (int r = 0; r < 16; ++r) {
        int il = r * 4 + ty;
        t[il][tx] = g_Yt[((size_t)b * I_DIM + i0 + il) * SEQ + n0 + tx];
    }
    __syncthreads();
    float* yb = y + (size_t)b * SEQ * I_DIM;
#pragma unroll
    for (int r = 0; r < 16; ++r) {
        int nl = r * 4 + ty;
        yb[(size_t)(n0 + nl) * I_DIM + i0 + tx] = t[tx][nl];
    }
}

// ---------------------------------------------------------------------------
extern "C" void kernel_launch(void* const* d_in, const int* in_sizes, int n_in,
                              void* d_out, int out_size, void* d_ws, size_t ws_size,
                              hipStream_t stream) {
    const float* x  = (const float*)d_in[0];
    const float* Bm = (const float*)d_in[1];
    const float* Cm = (const float*)d_in[2];
    const float* Lm = (const float*)d_in[3];
    const float* Pm = (const float*)d_in[4];
    const float* Qm = (const float*)d_in[5];
    float* out = (float*)d_out;

    k1_kprep_transpose<<<I_DIM + BATCH * I_DIM, 512, 0, stream>>>(x, Bm, Cm, Lm, Pm, Qm);
    k2_fused_conv<<<BATCH * I_DIM, 512, 0, stream>>>();
    k3_transpose_out<<<1024, 256, 0, stream>>>(out);
}

// Round 13
// 71.682 us; speedup vs baseline: 1.1567x; 1.1098x over previous
//
#include <hip/hip_runtime.h>

#define I_DIM 128
#define H_DIM 64
#define BATCH 8
#define SEQ   4096
#define NBIN  (SEQ/2 + 1)     // 2049
#define NBIN2 (SEQ + 1)       // 4097

// 3-nibble XOR swizzle: bijective on [0,4096); makes S1 (16u+k), S16 and
// S256 read/write patterns all land at the 4-lanes/bank-pair b64 ideal.
#define SZ(a) ((a) ^ (((a) >> 4) & 15) ^ (((a) >> 8) & 15))

// Module-scope device scratch (graph-capture safe, fully rewritten per call).
__device__ float  g_xT[(size_t)BATCH * I_DIM * SEQ];   // x transposed, 16.8 MB
__device__ float2 g_Hh[I_DIM * NBIN];                  // K_hat, 2.1 MB
__device__ float2 g_Kf[I_DIM * NBIN2];                 // 4.2 MB
__device__ float2 g_Xf[(size_t)BATCH * I_DIM * SEQ];   // fwd spectra, 33.5 MB
__device__ float  g_Yt[(size_t)BATCH * I_DIM * SEQ];   // y transposed, 16.8 MB

__device__ inline float2 cmul(float2 a, float2 b) {
    return make_float2(a.x * b.x - a.y * b.y, a.x * b.y + a.y * b.x);
}
__device__ inline float2 cadd(float2 a, float2 b) { return make_float2(a.x + b.x, a.y + b.y); }
__device__ inline float2 csub(float2 a, float2 b) { return make_float2(a.x - b.x, a.y - b.y); }

// DFT8 — proven r4-r12.
__device__ inline void dft8(float2 a[8]) {
    const float C = 0.70710678118654752f;
    float2 s0 = cadd(a[0], a[4]), s1 = cadd(a[1], a[5]);
    float2 s2 = cadd(a[2], a[6]), s3 = cadd(a[3], a[7]);
    float2 d0 = csub(a[0], a[4]), d1 = csub(a[1], a[5]);
    float2 d2 = csub(a[2], a[6]), d3 = csub(a[3], a[7]);
    d1 = make_float2(C * (d1.x + d1.y), C * (d1.y - d1.x));
    d2 = make_float2(d2.y, -d2.x);
    d3 = make_float2(C * (d3.y - d3.x), -C * (d3.x + d3.y));
    {
        float2 p0 = cadd(s0, s2), p1 = cadd(s1, s3);
        float2 m0 = csub(s0, s2), m1 = csub(s1, s3);
        m1 = make_float2(m1.y, -m1.x);
        a[0] = cadd(p0, p1); a[4] = csub(p0, p1);
        a[2] = cadd(m0, m1); a[6] = csub(m0, m1);
    }
    {
        float2 p0 = cadd(d0, d2), p1 = cadd(d1, d3);
        float2 m0 = csub(d0, d2), m1 = csub(d1, d3);
        m1 = make_float2(m1.y, -m1.x);
        a[1] = cadd(p0, p1); a[5] = csub(p0, p1);
        a[3] = cadd(m0, m1); a[7] = csub(m0, m1);
    }
}

// DFT8 of (x0,x1,x2,x3,0,0,0,0) — proven r8-r12 (halfzero trick).
__device__ inline void dft8hz(float2 x0, float2 x1, float2 x2, float2 x3,
                              float2 b[8]) {
    const float C = 0.70710678118654752f;
    float2 p0 = cadd(x0, x2), p1 = cadd(x1, x3);
    float2 m0 = csub(x0, x2), m1t = csub(x1, x3);
    float2 m1 = make_float2(m1t.y, -m1t.x);
    b[0] = cadd(p0, p1); b[4] = csub(p0, p1);
    b[2] = cadd(m0, m1); b[6] = csub(m0, m1);
    float2 c1 = make_float2(C * (x1.x + x1.y), C * (x1.y - x1.x));
    float2 c2 = make_float2(x2.y, -x2.x);
    float2 c3 = make_float2(C * (x3.y - x3.x), -C * (x3.x + x3.y));
    float2 q0 = cadd(x0, c2), q1 = cadd(c1, c3);
    float2 n0 = csub(x0, c2), n1t = csub(c1, c3);
    float2 n1 = make_float2(n1t.y, -n1t.x);
    b[1] = cadd(q0, q1); b[5] = csub(q0, q1);
    b[3] = cadd(n0, n1); b[7] = csub(n0, n1);
}

// DIT combine: b[k] = e[k] + W16^k o[k], b[k+8] = e[k] - W16^k o[k].
__device__ inline void combine16(const float2 e[8], const float2 o[8],
                                 float2 b[16]) {
    const float C  = 0.70710678118654752f;
    const float C1 = 0.92387953251128674f;   // cos(pi/8)
    const float S1 = 0.38268343236508977f;   // sin(pi/8)
    float2 t;
    b[0] = cadd(e[0], o[0]);  b[8]  = csub(e[0], o[0]);
    t = cmul(o[1], make_float2( C1, -S1)); b[1] = cadd(e[1], t); b[9]  = csub(e[1], t);
    t = cmul(o[2], make_float2(  C,  -C)); b[2] = cadd(e[2], t); b[10] = csub(e[2], t);
    t = cmul(o[3], make_float2( S1, -C1)); b[3] = cadd(e[3], t); b[11] = csub(e[3], t);
    t = make_float2(o[4].y, -o[4].x);      b[4] = cadd(e[4], t); b[12] = csub(e[4], t);
    t = cmul(o[5], make_float2(-S1, -C1)); b[5] = cadd(e[5], t); b[13] = csub(e[5], t);
    t = cmul(o[6], make_float2( -C,  -C)); b[6] = cadd(e[6], t); b[14] = csub(e[6], t);
    t = cmul(o[7], make_float2(-C1, -S1)); b[7] = cadd(e[7], t); b[15] = csub(e[7], t);
}

// DFT16 = 2x proven DFT8 + constant combine (DIT). Natural order in/out.
__device__ inline void dft16(float2 a[16]) {
    float2 e[8] = {a[0], a[2], a[4], a[6], a[8], a[10], a[12], a[14]};
    float2 o[8] = {a[1], a[3], a[5], a[7], a[9], a[11], a[13], a[15]};
    dft8(e); dft8(o);
    combine16(e, o, a);
}

// S1-fused write: b_k *= W4096^(u*k), store at SZ(16u+k). Upper half via
// w8*wk (register-lean).
__device__ inline void s1_twiddle_write(float2* __restrict__ lds, int u,
                                        float2 b[16]) {
    float sn, cs;
    __sincosf((float)(-6.283185307179586 / 4096.0) * (float)u, &sn, &cs);
    float2 w1 = make_float2(cs, sn);
    float2 w2 = cmul(w1, w1), w3 = cmul(w2, w1), w4 = cmul(w2, w2);
    float2 w5 = cmul(w3, w2), w6 = cmul(w3, w3), w7 = cmul(w4, w3);
    float2 w8 = cmul(w4, w4);
    const int base = 16 * u;
    lds[SZ(base + 0)]  = b[0];
    lds[SZ(base + 1)]  = cmul(b[1], w1);
    lds[SZ(base + 2)]  = cmul(b[2], w2);
    lds[SZ(base + 3)]  = cmul(b[3], w3);
    lds[SZ(base + 4)]  = cmul(b[4], w4);
    lds[SZ(base + 5)]  = cmul(b[5], w5);
    lds[SZ(base + 6)]  = cmul(b[6], w6);
    lds[SZ(base + 7)]  = cmul(b[7], w7);
    lds[SZ(base + 8)]  = cmul(b[8], w8);
    lds[SZ(base + 9)]  = cmul(cmul(b[9],  w1), w8);
    lds[SZ(base + 10)] = cmul(cmul(b[10], w2), w8);
    lds[SZ(base + 11)] = cmul(cmul(b[11], w3), w8);
    lds[SZ(base + 12)] = cmul(cmul(b[12], w4), w8);
    lds[SZ(base + 13)] = cmul(cmul(b[13], w5), w8);
    lds[SZ(base + 14)] = cmul(cmul(b[14], w6), w8);
    lds[SZ(base + 15)] = cmul(cmul(b[15], w7), w8);
}

// Radix-16 Stockham stage, N=4096, NB=256, 256 threads (u = tid).
// Same formula family as the HW-verified R=2/4/8 stages:
// q=u&(S-1); y[16u-15q+kS] = (dft16(x[u+256j]))_k * W4096^{k(u-q)}.
template <int S>
__device__ inline void stage16(float2* __restrict__ lds, int u) {
    float2 d[16];
#pragma unroll
    for (int j = 0; j < 16; ++j) d[j] = lds[SZ(u + 256 * j)];
    __syncthreads();
    const int q = u & (S - 1);
    dft16(d);
    if constexpr (S < 256) {
        float sn, cs;
        __sincosf((float)(-6.283185307179586 / 4096.0) * (float)(u - q), &sn, &cs);
        float2 w1 = make_float2(cs, sn);
        float2 w2 = cmul(w1, w1), w3 = cmul(w2, w1), w4 = cmul(w2, w2);
        float2 w5 = cmul(w3, w2), w6 = cmul(w3, w3), w7 = cmul(w4, w3);
        float2 w8 = cmul(w4, w4);
        d[1]  = cmul(d[1], w1);  d[2]  = cmul(d[2], w2);
        d[3]  = cmul(d[3], w3);  d[4]  = cmul(d[4], w4);
        d[5]  = cmul(d[5], w5);  d[6]  = cmul(d[6], w6);
        d[7]  = cmul(d[7], w7);  d[8]  = cmul(d[8], w8);
        d[9]  = cmul(cmul(d[9],  w1), w8);
        d[10] = cmul(cmul(d[10], w2), w8);
        d[11] = cmul(cmul(d[11], w3), w8);
        d[12] = cmul(cmul(d[12], w4), w8);
        d[13] = cmul(cmul(d[13], w5), w8);
        d[14] = cmul(cmul(d[14], w6), w8);
        d[15] = cmul(cmul(d[15], w7), w8);
    }
    const int base = 16 * u - 15 * q;
#pragma unroll
    for (int k = 0; k < 16; ++k)
        lds[SZ(base + k * S)] = d[k];
    __syncthreads();
}

// K_hat single bin — proven r2-r12.
__device__ inline float2 khat_bin(int i, int k,
                                  const float* __restrict__ Bm,
                                  const float* __restrict__ Cm,
                                  const float* __restrict__ Lm,
                                  const float* __restrict__ Pm,
                                  const float* __restrict__ Qm) {
    float theta = (float)(6.283185307179586 / (double)SEQ) * (float)k;
    float sn, cs;
    sincosf(theta, &sn, &cs);
    float tr = 1.0f - cs, ti = -sn;
    float br = 1.0f + cs, bi = sn;
    float idn = 1.0f / (br * br + bi * bi);
    float gr = 20.0f * (tr * br + ti * bi) * idn;
    float gi = 20.0f * (ti * br - tr * bi) * idn;
    float cr = 2.0f * br * idn;
    float ci = -2.0f * bi * idn;

    const float* Brow = Bm + i * H_DIM;
    const float* Crow = Cm + i * H_DIM;
    const float* Lrow = Lm + i * H_DIM;
    const float* Prow = Pm + i * H_DIM;
    const float* Qrow = Qm + i * H_DIM;

    float k00r = 0.f, k00i = 0.f, k01r = 0.f, k01i = 0.f;
    float k10r = 0.f, k10i = 0.f, k11r = 0.f, k11i = 0.f;
#pragma unroll 8
    for (int h = 0; h < H_DIM; ++h) {
        float lam = Lrow[h];
        float drr = gr - lam;
        float dii = gi;
        float im = 1.0f / (drr * drr + dii * dii);
        float ivr = drr * im;
        float ivi = -dii * im;
        float bv = Brow[h], cv = Crow[h], pv = Prow[h], qv = Qrow[h];
        float cb = cv * bv;
        float cp = cv * pv;
        float qb = qv * bv;
        float qp = qv * pv;
        k00r += cb * ivr; k00i += cb * ivi;
        k01r += cp * ivr; k01i += cp * ivi;
        k10r += qb * ivr; k10i += qb * ivi;
        k11r += qp * ivr; k11i += qp * ivi;
    }
    float t1r = 1.0f + k11r, t1i = k11i;
    float t2r = k01r * t1r - k01i * t1i;
    float t2i = k01r * t1i + k01i * t1r;
    float t3r = t2r * k10r - t2i * k10i;
    float t3i = t2r * k10i + t2i * k10r;
    float nr = k00r - t3r, ni = k00i - t3i;
    return make_float2(cr * nr - ci * ni, cr * ni + ci * nr);
}

// ===========================================================================
// Kernel 1: tiled transpose x -> xT + khat spread over 1024 blocks (r10
// verbatim — proven).
// ===========================================================================
__global__ __launch_bounds__(256) void k1_transpose_khat(const float* __restrict__ x,
                                                         const float* __restrict__ Bm,
                                                         const float* __restrict__ Cm,
                                                         const float* __restrict__ Lm,
                                                         const float* __restrict__ Pm,
                                                         const float* __restrict__ Qm) {
    __shared__ float t[64][65];
    const int blk = blockIdx.x;
    const int b = blk >> 7;
    const int rest = blk & 127;
    const int nt = rest >> 1;
    const int it = rest & 1;
    const int tx = threadIdx.x & 63;
    const int ty = threadIdx.x >> 6;
    const int n0 = nt * 64, i0 = it * 64;

    const float* xb = x + (size_t)b * SEQ * I_DIM;
#pragma unroll
    for (int r = 0; r < 16; ++r) {
        int nl = r * 4 + ty;
        t[nl][tx] = xb[(size_t)(n0 + nl) * I_DIM + i0 + tx];
    }
    __syncthreads();
#pragma unroll
    for (int r = 0; r < 16; ++r) {
        int il = r * 4 + ty;
        g_xT[((size_t)b * I_DIM + i0 + il) * SEQ + n0 + tx] = t[tx][il];
    }

    const int ch = blk >> 3, sl = blk & 7;
    const int k = sl * 256 + threadIdx.x;
    g_Hh[(size_t)ch * NBIN + k] = khat_bin(ch, k, Bm, Cm, Lm, Pm, Qm);
    if (sl == 0 && threadIdx.x == 0)
        g_Hh[(size_t)ch * NBIN + 2048] = khat_bin(ch, 2048, Bm, Cm, Lm, Pm, Qm);
}

// ===========================================================================
// Kernel 2 (256 threads): blocks [0,128) -> kprep-16:
//     Kf[2r] = H_ext[r]                        (even bins FREE — exact identity)
//     Kf[2r+1] = cfft4096(K[n] * W8192^n)[r]   (r < 2048)
//     where K = icfft4096(H_ext) (conj trick; K real -> take .x).
//   blocks [128,1152) -> fwd cfft4096 of xT row (halfzero16 S1) -> g_Xf.
// ===========================================================================
__global__ __launch_bounds__(256) void k2_kprep_fwd() {
    __shared__ float2 L[4096];
    const int u = threadIdx.x;           // 0..255

    if (blockIdx.x < I_DIM) {
        const int i = blockIdx.x;
        const float2* Hrow = g_Hh + (size_t)i * NBIN;

        // ---- phase A: icfft4096 of H_ext (conj trick), S1 fused ----
        {
            float2 d[16];
#pragma unroll
            for (int j = 0; j < 16; ++j) {
                int m = u + (j << 8);
                float2 h;
                if (m <= 2048) h = Hrow[m];
                else { float2 tt = Hrow[4096 - m]; h = make_float2(tt.x, -tt.y); }
                d[j] = make_float2(h.x, -h.y);   // conj(H_ext)
            }
            dft16(d);
            s1_twiddle_write(L, u, d);
            __syncthreads();
        }
        stage16<16>(L, u);
        stage16<256>(L, u);                  // R[n] natural order; K = R.x/4096

        // ---- phase B: v[n] = (R[n].x/4096) * W8192^n, S1 fused ----
        {
            const float2 W32[16] = {
                make_float2( 1.00000000f,  0.00000000f), make_float2( 0.98078528f, -0.19509032f),
                make_float2( 0.92387953f, -0.38268343f), make_float2( 0.83146961f, -0.55557023f),
                make_float2( 0.70710678f, -0.70710678f), make_float2( 0.55557023f, -0.83146961f),
                make_float2( 0.38268343f, -0.92387953f), make_float2( 0.19509032f, -0.98078528f),
                make_float2( 0.00000000f, -1.00000000f), make_float2(-0.19509032f, -0.98078528f),
                make_float2(-0.38268343f, -0.92387953f), make_float2(-0.55557023f, -0.83146961f),
                make_float2(-0.70710678f, -0.70710678f), make_float2(-0.83146961f, -0.55557023f),
                make_float2(-0.92387953f, -0.38268343f), make_float2(-0.98078528f, -0.19509032f)};
            float snu, csu;
            __sincosf((float)(-3.141592653589793 / 4096.0) * (float)u, &snu, &csu);
            float2 wu = make_float2(csu, snu);   // W8192^u
            float2 v[16];
#pragma unroll
            for (int j = 0; j < 16; ++j) {
                float kr = L[SZ(u + (j << 8))].x * (1.0f / 4096.0f);
                float2 w = cmul(wu, W32[j]);     // W8192^(u+256j)
                v[j] = make_float2(kr * w.x, kr * w.y);
            }
            __syncthreads();
            dft16(v);
            s1_twiddle_write(L, u, v);
            __syncthreads();
        }
        stage16<16>(L, u);

        // ---- final S256 (twiddle-free) fused with odd-bin store ----
        float2 e[16];
#pragma unroll
        for (int j = 0; j < 16; ++j) e[j] = L[SZ(u + (j << 8))];
        dft16(e);
        float2* Kfrow = g_Kf + (size_t)i * NBIN2;
#pragma unroll
        for (int k = 0; k < 8; ++k)              // r = u+256k < 2048
            Kfrow[2 * (u + (k << 8)) + 1] = e[k];
        // even bins: exact copy of H_ext
        for (int r = u; r <= 2048; r += 256)
            Kfrow[2 * r] = Hrow[r];
    } else {
        // ---------------- forward FFT of x row ----------------
        const int blk = blockIdx.x - I_DIM;      // 0..1023
        const int b = blk & 7;                   // batch -> XCD affinity
        const int i = blk >> 3;
        const float2* xrow = (const float2*)(g_xT + ((size_t)b * I_DIM + i) * SEQ);

        float2 xx[8];
#pragma unroll
        for (int j = 0; j < 8; ++j) xx[j] = xrow[u + (j << 8)];
        // halfzero16: E/O from proven dft8hz, constant combine, S1 twiddle
        float2 e[8], o[8], bb[16];
        dft8hz(xx[0], xx[2], xx[4], xx[6], e);
        dft8hz(xx[1], xx[3], xx[5], xx[7], o);
        combine16(e, o, bb);
        s1_twiddle_write(L, u, bb);
        __syncthreads();

        stage16<16>(L, u);

        // final S256 (twiddle-free) fused with coalesced Xf store
        float2 f[16];
#pragma unroll
        for (int j = 0; j < 16; ++j) f[j] = L[SZ(u + (j << 8))];
        dft16(f);
        float2* dst = g_Xf + (size_t)blk * SEQ;
#pragma unroll
        for (int k = 0; k < 16; ++k)
            dst[u + (k << 8)] = f[k];
    }
}

// ===========================================================================
// Kernel 3 (256 threads): fused combine (r9 formula) + inverse cfft4096
// (conj trick) -> coalesced yT store. 3 LDS touches total.
// ===========================================================================
__global__ __launch_bounds__(256) void k3_combine_inv() {
    __shared__ float2 L[4096];
    const int u = threadIdx.x;
    const int blk = blockIdx.x;
    const int b = blk & 7;
    const int i = blk >> 3;
    const float2* Xf = g_Xf + (size_t)blk * SEQ;
    const float2* Kfrow = g_Kf + (size_t)i * NBIN2;

    float2 d[16];
#pragma unroll
    for (int j = 0; j < 16; ++j) {
        int m = u + (j << 8);
        int mm = (4096 - m) & 4095;
        float2 Zq = Xf[m];
        float2 Zr = Xf[mm];
        float2 Km  = Kfrow[m];
        float2 Km2 = Kfrow[4096 - m];
        float sn, cs;
        __sincosf((float)(-3.141592653589793 / 4096.0) * (float)m, &sn, &cs);
        float pr = Zq.x + Zr.x, pi2 = Zq.y - Zr.y;
        float dr = Zq.x - Zr.x, di = Zq.y + Zr.y;
        float jt_r = -sn * dr - cs * di;
        float jt_i =  cs * dr - sn * di;
        float2 Xm  = make_float2(0.5f * (pr - jt_r),  0.5f * ( pi2 - jt_i));
        float2 Xm2 = make_float2(0.5f * (pr + jt_r),  0.5f * (-pi2 - jt_i));
        float2 Ym  = cmul(Xm,  Km);
        float2 Ym2 = cmul(Xm2, Km2);
        float qr = Ym.x + Ym2.x, qi = Ym.y - Ym2.y;
        float er = Ym.x - Ym2.x, ei = Ym.y + Ym2.y;
        float gr2 = sn * er - cs * ei;
        float gi2 = sn * ei + cs * er;
        d[j] = make_float2(0.5f * (qr + gr2), -0.5f * (qi + gi2));  // conjZy[m]
    }
    dft16(d);
    s1_twiddle_write(L, u, d);
    __syncthreads();

    stage16<16>(L, u);

    // final S256 (twiddle-free) fused with yT store; only n < 2048 needed
    float2 e[16];
#pragma unroll
    for (int j = 0; j < 16; ++j) e[j] = L[SZ(u + (j << 8))];
    dft16(e);
    const float inv = 1.0f / 4096.0f;
    float2* yrow = (float2*)(g_Yt + ((size_t)b * I_DIM + i) * SEQ);
#pragma unroll
    for (int k = 0; k < 8; ++k)                  // n = u+256k < 2048
        yrow[u + (k << 8)] = make_float2(e[k].x * inv, -e[k].y * inv);
}

// ===========================================================================
// Kernel 4: tiled transpose yT -> y (r10 verbatim — proven).
// ===========================================================================
__global__ __launch_bounds__(256) void k4_transpose_out(float* __restrict__ y) {
    __shared__ float t[64][65];
    const int blk = blockIdx.x;
    const int b = blk >> 7;
    const int rest = blk & 127;
    const int nt = rest >> 1;
    const int it = rest & 1;
    const int tx = threadIdx.x & 63;
    const int ty = threadIdx.x >> 6;
    const int n0 = nt * 64, i0 = it * 64;

#pragma unroll
    for (int r = 0; r < 16; ++r) {
        int il = r * 4 + ty;
        t[il][tx] = g_Yt[((size_t)b * I_DIM + i0 + il) * SEQ + n0 + tx];
    }
    __syncthreads();
    float* yb = y + (size_t)b * SEQ * I_DIM;
#pragma unroll
    for (int r = 0; r < 16; ++r) {
        int nl = r * 4 + ty;
        yb[(size_t)(n0 + nl) * I_DIM + i0 + tx] = t[tx][nl];
    }
}

// ---------------------------------------------------------------------------
extern "C" void kernel_launch(void* const* d_in, const int* in_sizes, int n_in,
                              void* d_out, int out_size, void* d_ws, size_t ws_size,
                              hipStream_t stream) {
    const float* x  = (const float*)d_in[0];
    const float* Bm = (const float*)d_in[1];
    const float* Cm = (const float*)d_in[2];
    const float* Lm = (const float*)d_in[3];
    const float* Pm = (const float*)d_in[4];
    const float* Qm = (const float*)d_in[5];
    float* out = (float*)d_out;

    k1_transpose_khat<<<1024, 256, 0, stream>>>(x, Bm, Cm, Lm, Pm, Qm);
    k2_kprep_fwd<<<I_DIM + BATCH * I_DIM, 256, 0, stream>>>();
    k3_combine_inv<<<BATCH * I_DIM, 256, 0, stream>>>();
    k4_transpose_out<<<1024, 256, 0, stream>>>(out);
}